// Round 3
// baseline (152.841 us; speedup 1.0000x reference)
//
#include <hip/hip_runtime.h>
#include <math.h>

#define BB 512
#define DD 16
#define NN 64
#define MM 32
#define RR 32
#define CC 10
#define BBLK 16          // b's per chain block (8 waves, 2 chains/wave)
#define ROWH 40          // halves per LDS row (80 B, 16B-aligned)
#define BREGH 1304       // halves per b region

typedef _Float16 v8h __attribute__((ext_vector_type(8)));
typedef float v4f __attribute__((ext_vector_type(4)));

union H8 { unsigned int u[4]; v8h h; _Float16 e[8]; };
union H4 { unsigned int u[2]; _Float16 e[4]; };

// ---------------------------------------------------------------------------
// Kernel 1 (unchanged): merged producers, all coalesced via LDS staging.
// ---------------------------------------------------------------------------
__global__ __launch_bounds__(256) void produce_kernel(
    const float* __restrict__ tensor, const float* __restrict__ W,
    const float* __restrict__ bias,   const float* __restrict__ G,
    _Float16* __restrict__ fh,        _Float16* __restrict__ gh) {
    __shared__ __align__(16) char smem[36864];
    const int t = threadIdx.x;
    if (blockIdx.x < 1024) {
        float* ten_s = (float*)smem;          // [8][64]
        float* W_s   = (float*)smem + 512;    // [64][32]
        const int bd0 = blockIdx.x * 8;
        if (t < 128)
            *(float4*)(ten_s + t * 4) = *(const float4*)(tensor + bd0 * NN + t * 4);
        *(float4*)(W_s + t * 4)        = *(const float4*)(W + t * 4);
        *(float4*)(W_s + 1024 + t * 4) = *(const float4*)(W + 1024 + t * 4);
        __syncthreads();
        const int m = t & 31, bd_l = t >> 5;
        float acc = bias[m];
#pragma unroll
        for (int n = 0; n < NN; ++n) acc += ten_s[bd_l * NN + n] * W_s[n * MM + m];
        fh[(bd0 + bd_l) * MM + m] = (_Float16)acc;
    } else {
        _Float16* lg = (_Float16*)smem;       // [di][m][j], m-stride 36 halves
        const int pb = blockIdx.x - 1024;     // 0..319
        const int c  = pb >> 5;
        const int d  = (pb >> 1) & 15;
        const int hf = pb & 1;
        const float* src = G + (size_t)(c * DD + d) * 32768 + hf * 16384;
#pragma unroll
        for (int k = 0; k < 16; ++k) {        // coalesced read of 64 KB slab-half
            const int f = (k * 256 + t) * 4;
            float4 v = *(const float4*)(src + f);
            const int di = f >> 10, m = (f >> 5) & 31, j = f & 31;
            H4 hv;
            hv.e[0] = (_Float16)v.x; hv.e[1] = (_Float16)v.y;
            hv.e[2] = (_Float16)v.z; hv.e[3] = (_Float16)v.w;
            *(uint2*)(lg + di * 1152 + m * 36 + j) = make_uint2(hv.u[0], hv.u[1]);
        }
        __syncthreads();
#pragma unroll
        for (int k = 0; k < 8; ++k) {         // coalesced 16B fragment writes
            const int idx = k * 256 + t;
            const int tl = idx >> 6, ln = idx & 63;
            const int di = tl >> 1, jh = tl & 1;
            const int q = ln >> 4, j4 = ln & 15;
            const int j = jh * 16 + j4;
            H8 o;
#pragma unroll
            for (int r = 0; r < 8; ++r)
                o.e[r] = lg[di * 1152 + (8 * q + r) * 36 + j];
            const size_t gi = ((size_t)(c * DD + d) * 64 + hf * 32 + tl) * 64 + ln;
            *(v8h*)(gh + gi * 8) = o.h;
        }
    }
}

// ---------------------------------------------------------------------------
// Kernel 2 (fused): per (c, b-block of 16): all 16 d's, both chain segments,
// and the trace — no segP round trip.
// Chain state kept TRANSPOSED: S_d = C_d^T * S_{d-1}  (state = P^T as MFMA
// B-fragment). The C-layout MFMA output's in-lane contiguous direction (rows
// 4q+reg) is the k-direction of the next B-frag, so the per-d state round
// trip is 4 packed ds_write_b64 + 2 ds_read_b128 (vs 16 scalar b16 before).
// A-operand C_d^T comes from the same L[b][j][i] core layout via the same
// b128 read as before. At d=7, M holds P0 row-major; 16 scalar u16 reads per
// chain capture exactly the elements that pair per-lane with the d=15
// accumulator: tr += acc1[jt][vt][reg] * P0[16jt+4q+reg][16vt+j4].
// State scratch overlays the chain's own core region (state lives in LDS only
// transiently within phase 2 — written packed, immediately re-read into regs —
// so next phase 1 may freely overwrite), LDS stays 41728 B.
// ---------------------------------------------------------------------------
__global__ __launch_bounds__(512, 4) void chain_kernel(
    const _Float16* __restrict__ feat_h,
    const _Float16* __restrict__ g_h,
    float* __restrict__ trout)         // [B][C] fp32 traces
{
    __shared__ __align__(16) _Float16 lds[BBLK * BREGH];  // 41728 B

    const int bid = blockIdx.x;        // 0..319
    const int xcd = bid & 7;
    const int idx = bid >> 3;          // 0..39
    int c, sub;
    if (idx < 32) { c = xcd; sub = idx; }
    else {
        const int e = idx - 32;        // 0..7
        if (xcd >= 2 && xcd <= 5) { c = 8; sub = (xcd - 2) * 8 + e; }
        else                      { c = 9; sub = (((xcd + 2) & 7)) * 8 + e; }
    }
    const int b0 = sub * BBLK;
    const int t    = threadIdx.x;
    const int w    = t >> 6;           // wave 0..7
    const int lane = t & 63;
    const int q    = lane >> 4;
    const int j4   = lane & 15;

    const int bA = b0 + j4;            // all 16 A rows valid
    const size_t gc = (size_t)c * DD * 32768;

    // prefetch d=0 fragments
    v8h afh = *(const v8h*)(feat_h + (size_t)bA * (DD * MM) + 0 * MM + q * 8);
    v8h gf[8];
#pragma unroll
    for (int u = 0; u < 8; ++u)
        gf[u] = *(const v8h*)(g_h + gc + ((size_t)(w * 8 + u) * 64 + lane) * 8);

    v8h sb[2][2];                      // [chain cc][vt]  state B-frags
    uint2 p0u[2][2][2];                // [cc][jt][vt]    P0 elems (4 halves ea)

    for (int d = 0; d < DD; ++d) {
        __syncthreads();   // WAR: previous phase-2 LDS use done
        // ---- phase 1: 8 MFMAs on prefetched fragments --------------------
        v4f av[8];
#pragma unroll
        for (int u = 0; u < 8; ++u) {
            v4f z = {0.f, 0.f, 0.f, 0.f};
            av[u] = __builtin_amdgcn_mfma_f32_16x16x32_f16(afh, gf[u], z, 0, 0, 0);
        }
        if (d < DD - 1) {              // prefetch d+1 (overlaps phase 2)
            afh = *(const v8h*)(feat_h + (size_t)bA * (DD * MM) + (d + 1) * MM + q * 8);
            const size_t gb = gc + (size_t)(d + 1) * 32768;
#pragma unroll
            for (int u = 0; u < 8; ++u)
                gf[u] = *(const v8h*)(g_h + gb + ((size_t)(w * 8 + u) * 64 + lane) * 8);
        }
        // store cores: L[b=4q+reg][j][i], i = 4w+ii contiguous
#pragma unroll
        for (int jh = 0; jh < 2; ++jh)
#pragma unroll
            for (int reg = 0; reg < 4; ++reg) {
                H4 hv;
                hv.e[0] = (_Float16)av[0 + jh][reg];
                hv.e[1] = (_Float16)av[2 + jh][reg];
                hv.e[2] = (_Float16)av[4 + jh][reg];
                hv.e[3] = (_Float16)av[6 + jh][reg];
                *(uint2*)(&lds[(4 * q + reg) * BREGH + (16 * jh + j4) * ROWH + 4 * w]) =
                    make_uint2(hv.u[0], hv.u[1]);
            }
        __syncthreads();   // cores ready
        // ---- phase 2: wave w advances chains b = 2w, 2w+1 ----------------
#pragma unroll
        for (int cc = 0; cc < 2; ++cc) {
            const int bl = 2 * w + cc;
            _Float16* base = lds + bl * BREGH;
            if (d == 0 || d == 8) {
                // init S = C_d^T as B-frag: sb[vt][k=8q+r][col=16vt+j4]
                //   = C[16vt+j4][8q+r] = L[b][j=8q+r][i=16vt+j4]
#pragma unroll
                for (int vt = 0; vt < 2; ++vt) {
                    H8 x;
#pragma unroll
                    for (int r = 0; r < 8; ++r)
                        x.e[r] = base[(8 * q + r) * ROWH + 16 * vt + j4];
                    sb[cc][vt] = x.h;
                }
            } else {
                // A = C_d^T frags (same b128 read as the old B-frag read)
                v8h af2[2];
#pragma unroll
                for (int jt = 0; jt < 2; ++jt)
                    af2[jt] = *(const v8h*)(base + (16 * jt + j4) * ROWH + 8 * q);
                v4f acc[2][2];
#pragma unroll
                for (int jt = 0; jt < 2; ++jt)
#pragma unroll
                    for (int vt = 0; vt < 2; ++vt) {
                        v4f z = {0.f, 0.f, 0.f, 0.f};
                        acc[jt][vt] = __builtin_amdgcn_mfma_f32_16x16x32_f16(
                            af2[jt], sb[cc][vt], z, 0, 0, 0);
                    }
                if (d == DD - 1) {
                    // trace: acc1 = P1^T (C-layout) pairs per-lane with p0u
                    float ts = 0.f;
#pragma unroll
                    for (int jt = 0; jt < 2; ++jt)
#pragma unroll
                        for (int vt = 0; vt < 2; ++vt) {
                            H4 pv;
                            pv.u[0] = p0u[cc][jt][vt].x;
                            pv.u[1] = p0u[cc][jt][vt].y;
#pragma unroll
                            for (int reg = 0; reg < 4; ++reg)
                                ts += acc[jt][vt][reg] * (float)pv.e[reg];
                        }
#pragma unroll
                    for (int off = 32; off > 0; off >>= 1)
                        ts += __shfl_xor(ts, off);
                    if (lane == 0) trout[(size_t)(b0 + bl) * CC + c] = ts;
                } else {
                    // write S_new packed: M[v=16vt+j4][j=16jt+4q+reg] (b64)
                    // (at d==7 this stores P0 row-major: M[r][c] = P0[r][c])
#pragma unroll
                    for (int jt = 0; jt < 2; ++jt)
#pragma unroll
                        for (int vt = 0; vt < 2; ++vt) {
                            H4 hv;
                            hv.e[0] = (_Float16)acc[jt][vt][0];
                            hv.e[1] = (_Float16)acc[jt][vt][1];
                            hv.e[2] = (_Float16)acc[jt][vt][2];
                            hv.e[3] = (_Float16)acc[jt][vt][3];
                            *(uint2*)(base + (16 * vt + j4) * ROWH + 16 * jt + 4 * q) =
                                make_uint2(hv.u[0], hv.u[1]);
                        }
                    __builtin_amdgcn_sched_barrier(0);
                    if (d == 7) {
                        // capture P0 elems that pair with the d=15 acc layout
#pragma unroll
                        for (int jt = 0; jt < 2; ++jt)
#pragma unroll
                            for (int vt = 0; vt < 2; ++vt) {
                                H4 pv;
#pragma unroll
                                for (int reg = 0; reg < 4; ++reg)
                                    pv.e[reg] =
                                        base[(16 * jt + 4 * q + reg) * ROWH + 16 * vt + j4];
                                p0u[cc][jt][vt] = make_uint2(pv.u[0], pv.u[1]);
                            }
                        // sb re-initialized from C8 at d==8
                    } else {
                        // re-read state as B-frags (b128)
#pragma unroll
                        for (int vt = 0; vt < 2; ++vt)
                            sb[cc][vt] = *(const v8h*)(base + (16 * vt + j4) * ROWH + 8 * q);
                    }
                }
            }
        }
    }
}

// ---------------------------------------------------------------------------
// Kernel 3: tiny log-softmax over the [B][C] trace buffer (20 KB).
// ---------------------------------------------------------------------------
__global__ __launch_bounds__(256) void lsm_kernel(
    const float* __restrict__ tr, float* __restrict__ out) {
    const int b = blockIdx.x * 256 + threadIdx.x;   // 2 blocks x 256 = 512
    float v[CC];
    float mx = -1e30f;
#pragma unroll
    for (int c = 0; c < CC; ++c) {
        v[c] = tr[b * CC + c];
        mx = fmaxf(mx, v[c]);
    }
    float ssum = 0.f;
#pragma unroll
    for (int c = 0; c < CC; ++c) ssum += expf(v[c] - mx);
    const float ls = logf(ssum);
#pragma unroll
    for (int c = 0; c < CC; ++c) out[b * CC + c] = v[c] - mx - ls;
}

// ---------------------------------------------------------------------------
extern "C" void kernel_launch(void* const* d_in, const int* in_sizes, int n_in,
                              void* d_out, int out_size, void* d_ws, size_t ws_size,
                              hipStream_t stream) {
    const float* tensor = (const float*)d_in[0];
    const float* W      = (const float*)d_in[1];
    const float* bias   = (const float*)d_in[2];
    const float* G      = (const float*)d_in[3];
    float* out = (float*)d_out;

    const size_t FEAT = (size_t)BB * DD * MM;          // 262144 halves
    const size_t GPK  = (size_t)CC * DD * 64 * 64 * 8; // 5242880 halves
    _Float16* fh = (_Float16*)d_ws;
    _Float16* gh = fh + FEAT;
    float* trbuf = (float*)(gh + GPK);                 // 512*10 fp32 (20 KB)

    produce_kernel<<<1024 + 320, 256, 0, stream>>>(tensor, W, bias, G, fh, gh);
    chain_kernel<<<CC * (BB / BBLK), 512, 0, stream>>>(fh, gh, trbuf);
    lsm_kernel<<<BB / 256, 256, 0, stream>>>(trbuf, out);
}

// Round 4
// 114.723 us; speedup vs baseline: 1.3323x; 1.3323x over previous
//
#include <hip/hip_runtime.h>
#include <math.h>

#define BB 512
#define DD 16
#define NN 64
#define MM 32
#define RR 32
#define CC 10
#define BBLK 16          // b's per chain block (8 waves, 2 chains/wave)
#define ROWH 40          // halves per LDS row (80 B, 16B-aligned)
#define BREGH 1304       // halves per b region

typedef _Float16 v8h __attribute__((ext_vector_type(8)));
typedef float v4f __attribute__((ext_vector_type(4)));

union H8 { unsigned int u[4]; v8h h; _Float16 e[8]; };
union H4 { unsigned int u[2]; _Float16 e[4]; };

// ---------------------------------------------------------------------------
// Kernel 1 (unchanged): merged producers, all coalesced via LDS staging.
// ---------------------------------------------------------------------------
__global__ __launch_bounds__(256) void produce_kernel(
    const float* __restrict__ tensor, const float* __restrict__ W,
    const float* __restrict__ bias,   const float* __restrict__ G,
    _Float16* __restrict__ fh,        _Float16* __restrict__ gh) {
    __shared__ __align__(16) char smem[36864];
    const int t = threadIdx.x;
    if (blockIdx.x < 1024) {
        float* ten_s = (float*)smem;          // [8][64]
        float* W_s   = (float*)smem + 512;    // [64][32]
        const int bd0 = blockIdx.x * 8;
        if (t < 128)
            *(float4*)(ten_s + t * 4) = *(const float4*)(tensor + bd0 * NN + t * 4);
        *(float4*)(W_s + t * 4)        = *(const float4*)(W + t * 4);
        *(float4*)(W_s + 1024 + t * 4) = *(const float4*)(W + 1024 + t * 4);
        __syncthreads();
        const int m = t & 31, bd_l = t >> 5;
        float acc = bias[m];
#pragma unroll
        for (int n = 0; n < NN; ++n) acc += ten_s[bd_l * NN + n] * W_s[n * MM + m];
        fh[(bd0 + bd_l) * MM + m] = (_Float16)acc;
    } else {
        _Float16* lg = (_Float16*)smem;       // [di][m][j], m-stride 36 halves
        const int pb = blockIdx.x - 1024;     // 0..319
        const int c  = pb >> 5;
        const int d  = (pb >> 1) & 15;
        const int hf = pb & 1;
        const float* src = G + (size_t)(c * DD + d) * 32768 + hf * 16384;
#pragma unroll
        for (int k = 0; k < 16; ++k) {        // coalesced read of 64 KB slab-half
            const int f = (k * 256 + t) * 4;
            float4 v = *(const float4*)(src + f);
            const int di = f >> 10, m = (f >> 5) & 31, j = f & 31;
            H4 hv;
            hv.e[0] = (_Float16)v.x; hv.e[1] = (_Float16)v.y;
            hv.e[2] = (_Float16)v.z; hv.e[3] = (_Float16)v.w;
            *(uint2*)(lg + di * 1152 + m * 36 + j) = make_uint2(hv.u[0], hv.u[1]);
        }
        __syncthreads();
#pragma unroll
        for (int k = 0; k < 8; ++k) {         // coalesced 16B fragment writes
            const int idx = k * 256 + t;
            const int tl = idx >> 6, ln = idx & 63;
            const int di = tl >> 1, jh = tl & 1;
            const int q = ln >> 4, j4 = ln & 15;
            const int j = jh * 16 + j4;
            H8 o;
#pragma unroll
            for (int r = 0; r < 8; ++r)
                o.e[r] = lg[di * 1152 + (8 * q + r) * 36 + j];
            const size_t gi = ((size_t)(c * DD + d) * 64 + hf * 32 + tl) * 64 + ln;
            *(v8h*)(gh + gi * 8) = o.h;
        }
    }
}

// ---------------------------------------------------------------------------
// Kernel 2 (fused, spill-free): per (c, b-block of 16): all 16 d's + trace.
// Transposed recurrence through the WHOLE chain: S_d = C_d^T * S_{d-1},
// S_15 = (C_0 ... C_15)^T = Ptot^T, and logits = tr(Ptot) = tr(Ptot^T) =
// sum of S_15's diagonal — no mid-chain P0 capture, no held p0u registers
// (that capture is what pushed the live set past the 128-reg budget and
// caused 19 MB of scratch writes in the previous version).
// Diagonal in C-layout: lane (q,j4) with j4 == 4q+reg holds Ptot^T[j4][j4]
// (tile 0,0) and Ptot^T[16+j4][16+j4] (tile 1,1) -> final d needs only the
// two diagonal-tile MFMAs.
// Per-d state round trip stays packed: 4 ds_write_b64 + 2 ds_read_b128.
// ---------------------------------------------------------------------------
__global__ __launch_bounds__(512, 4) void chain_kernel(
    const _Float16* __restrict__ feat_h,
    const _Float16* __restrict__ g_h,
    float* __restrict__ trout)         // [B][C] fp32 traces
{
    __shared__ __align__(16) _Float16 lds[BBLK * BREGH];  // 41728 B

    const int bid = blockIdx.x;        // 0..319
    const int xcd = bid & 7;
    const int idx = bid >> 3;          // 0..39
    int c, sub;
    if (idx < 32) { c = xcd; sub = idx; }
    else {
        const int e = idx - 32;        // 0..7
        if (xcd >= 2 && xcd <= 5) { c = 8; sub = (xcd - 2) * 8 + e; }
        else                      { c = 9; sub = (((xcd + 2) & 7)) * 8 + e; }
    }
    const int b0 = sub * BBLK;
    const int t    = threadIdx.x;
    const int w    = t >> 6;           // wave 0..7
    const int lane = t & 63;
    const int q    = lane >> 4;
    const int j4   = lane & 15;

    const int bA = b0 + j4;            // all 16 A rows valid
    const size_t gc = (size_t)c * DD * 32768;

    // prefetch d=0 fragments
    v8h afh = *(const v8h*)(feat_h + (size_t)bA * (DD * MM) + 0 * MM + q * 8);
    v8h gf[8];
#pragma unroll
    for (int u = 0; u < 8; ++u)
        gf[u] = *(const v8h*)(g_h + gc + ((size_t)(w * 8 + u) * 64 + lane) * 8);

    v8h sb[2][2];                      // [chain cc][vt]  state B-frags

    for (int d = 0; d < DD; ++d) {
        __syncthreads();   // WAR: previous phase-2 LDS use done
        // ---- phase 1: 8 MFMAs on prefetched fragments --------------------
        v4f av[8];
#pragma unroll
        for (int u = 0; u < 8; ++u) {
            v4f z = {0.f, 0.f, 0.f, 0.f};
            av[u] = __builtin_amdgcn_mfma_f32_16x16x32_f16(afh, gf[u], z, 0, 0, 0);
        }
        if (d < DD - 1) {              // prefetch d+1 (overlaps phase 2)
            afh = *(const v8h*)(feat_h + (size_t)bA * (DD * MM) + (d + 1) * MM + q * 8);
            const size_t gb = gc + (size_t)(d + 1) * 32768;
#pragma unroll
            for (int u = 0; u < 8; ++u)
                gf[u] = *(const v8h*)(g_h + gb + ((size_t)(w * 8 + u) * 64 + lane) * 8);
        }
        // store cores: L[b=4q+reg][j][i], i = 4w+ii contiguous
#pragma unroll
        for (int jh = 0; jh < 2; ++jh)
#pragma unroll
            for (int reg = 0; reg < 4; ++reg) {
                H4 hv;
                hv.e[0] = (_Float16)av[0 + jh][reg];
                hv.e[1] = (_Float16)av[2 + jh][reg];
                hv.e[2] = (_Float16)av[4 + jh][reg];
                hv.e[3] = (_Float16)av[6 + jh][reg];
                *(uint2*)(&lds[(4 * q + reg) * BREGH + (16 * jh + j4) * ROWH + 4 * w]) =
                    make_uint2(hv.u[0], hv.u[1]);
            }
        __syncthreads();   // cores ready
        // ---- phase 2: wave w advances chains b = 2w, 2w+1 ----------------
#pragma unroll
        for (int cc = 0; cc < 2; ++cc) {
            const int bl = 2 * w + cc;
            _Float16* base = lds + bl * BREGH;
            if (d == 0) {
                // init S = C_0^T as B-frag: sb[vt][k=8q+r][col=j4]
                //   = C^T[8q+r][16vt+j4] = L[b][j=8q+r][i=16vt+j4]
#pragma unroll
                for (int vt = 0; vt < 2; ++vt) {
                    H8 x;
#pragma unroll
                    for (int r = 0; r < 8; ++r)
                        x.e[r] = base[(8 * q + r) * ROWH + 16 * vt + j4];
                    sb[cc][vt] = x.h;
                }
            } else {
                // A = C_d^T frags (b128 reads)
                v8h af2[2];
#pragma unroll
                for (int jt = 0; jt < 2; ++jt)
                    af2[jt] = *(const v8h*)(base + (16 * jt + j4) * ROWH + 8 * q);
                if (d == DD - 1) {
                    // only the two diagonal tiles matter for the trace
                    v4f z0 = {0.f, 0.f, 0.f, 0.f};
                    v4f a0 = __builtin_amdgcn_mfma_f32_16x16x32_f16(
                        af2[0], sb[cc][0], z0, 0, 0, 0);
                    v4f z1 = {0.f, 0.f, 0.f, 0.f};
                    v4f a1 = __builtin_amdgcn_mfma_f32_16x16x32_f16(
                        af2[1], sb[cc][1], z1, 0, 0, 0);
                    float ts = 0.f;
#pragma unroll
                    for (int reg = 0; reg < 4; ++reg)
                        if (j4 == 4 * q + reg) ts = a0[reg] + a1[reg];
#pragma unroll
                    for (int off = 32; off > 0; off >>= 1)
                        ts += __shfl_xor(ts, off);
                    if (lane == 0) trout[(size_t)(b0 + bl) * CC + c] = ts;
                } else {
                    v4f acc[2][2];
#pragma unroll
                    for (int jt = 0; jt < 2; ++jt)
#pragma unroll
                        for (int vt = 0; vt < 2; ++vt) {
                            v4f z = {0.f, 0.f, 0.f, 0.f};
                            acc[jt][vt] = __builtin_amdgcn_mfma_f32_16x16x32_f16(
                                af2[jt], sb[cc][vt], z, 0, 0, 0);
                        }
                    // write S_new packed: M[v=16vt+j4][j=16jt+4q+reg] (b64)
#pragma unroll
                    for (int jt = 0; jt < 2; ++jt)
#pragma unroll
                        for (int vt = 0; vt < 2; ++vt) {
                            H4 hv;
                            hv.e[0] = (_Float16)acc[jt][vt][0];
                            hv.e[1] = (_Float16)acc[jt][vt][1];
                            hv.e[2] = (_Float16)acc[jt][vt][2];
                            hv.e[3] = (_Float16)acc[jt][vt][3];
                            *(uint2*)(base + (16 * vt + j4) * ROWH + 16 * jt + 4 * q) =
                                make_uint2(hv.u[0], hv.u[1]);
                        }
                    __builtin_amdgcn_sched_barrier(0);
                    // re-read state as B-frags (b128)
#pragma unroll
                    for (int vt = 0; vt < 2; ++vt)
                        sb[cc][vt] = *(const v8h*)(base + (16 * vt + j4) * ROWH + 8 * q);
                }
            }
        }
    }
}

// ---------------------------------------------------------------------------
// Kernel 3: tiny log-softmax over the [B][C] trace buffer (20 KB).
// ---------------------------------------------------------------------------
__global__ __launch_bounds__(256) void lsm_kernel(
    const float* __restrict__ tr, float* __restrict__ out) {
    const int b = blockIdx.x * 256 + threadIdx.x;   // 2 blocks x 256 = 512
    float v[CC];
    float mx = -1e30f;
#pragma unroll
    for (int c = 0; c < CC; ++c) {
        v[c] = tr[b * CC + c];
        mx = fmaxf(mx, v[c]);
    }
    float ssum = 0.f;
#pragma unroll
    for (int c = 0; c < CC; ++c) ssum += expf(v[c] - mx);
    const float ls = logf(ssum);
#pragma unroll
    for (int c = 0; c < CC; ++c) out[b * CC + c] = v[c] - mx - ls;
}

// ---------------------------------------------------------------------------
extern "C" void kernel_launch(void* const* d_in, const int* in_sizes, int n_in,
                              void* d_out, int out_size, void* d_ws, size_t ws_size,
                              hipStream_t stream) {
    const float* tensor = (const float*)d_in[0];
    const float* W      = (const float*)d_in[1];
    const float* bias   = (const float*)d_in[2];
    const float* G      = (const float*)d_in[3];
    float* out = (float*)d_out;

    const size_t FEAT = (size_t)BB * DD * MM;          // 262144 halves
    const size_t GPK  = (size_t)CC * DD * 64 * 64 * 8; // 5242880 halves
    _Float16* fh = (_Float16*)d_ws;
    _Float16* gh = fh + FEAT;
    float* trbuf = (float*)(gh + GPK);                 // 512*10 fp32 (20 KB)

    produce_kernel<<<1024 + 320, 256, 0, stream>>>(tensor, W, bias, G, fh, gh);
    chain_kernel<<<CC * (BB / BBLK), 512, 0, stream>>>(fh, gh, trbuf);
    lsm_kernel<<<BB / 256, 256, 0, stream>>>(trbuf, out);
}